// Round 6
// baseline (126.873 us; speedup 1.0000x reference)
//
#include <hip/hip_runtime.h>
#include <hip/hip_bf16.h>

#define NS 64
#define NP 32
#define DIM 128
#define BATCH_N 16384

typedef float f32x4 __attribute__((ext_vector_type(4)));
typedef _Float16 f16x8 __attribute__((ext_vector_type(8)));
typedef unsigned int u32;
typedef unsigned long long u64;

// fp32 -> fp16 (RNE via hardware cvt)
__device__ __forceinline__ unsigned short f2h(float f) {
    _Float16 h = (_Float16)f;
    return __builtin_bit_cast(unsigned short, h);
}

// ---------------------------------------------------------------------------
// prep 1: pair-compressed fp16 MFMA A-operand fragments (unchanged from R4).
// Pair p combines sites s0=2p, s1=2p+1. Terms:
//   t0 = A0@B0            t1 = (A1-A0)@B0      (factor b0)
//   t2 = A0@(B1-B0)       t3 = (A1-A0)@(B1-B0) (factor b0*b1)
// frag[p][t][kk][mm][lane][j], value = T[k][m],
// k = kk*32 + (lane>>4)*8 + j, m = mm*16 + (lane&15).
// ---------------------------------------------------------------------------
__global__ __launch_bounds__(256)
void prep_pair_frags(const float* __restrict__ data,
                     unsigned short* __restrict__ afrag) {
    __shared__ float LA[2 * 32 * 129];
    __shared__ float LB[2 * 32 * 128];

    const int p   = blockIdx.x >> 2;
    const int kk  = blockIdx.x & 3;
    const int tid = threadIdx.x;
    const int kgrp = tid >> 5;
    const int mgrp = tid & 31;

    const float* A0 = data + ((size_t)(2 * p) * 2 + 0) * DIM * DIM;
    const float* A1 = A0 + DIM * DIM;
    const float* B0 = data + ((size_t)(2 * p + 1) * 2 + 0) * DIM * DIM;
    const float* B1 = B0 + DIM * DIM;

    for (int c = tid; c < 32 * DIM; c += 256) {
        int kl = c >> 7, j = c & 127;
        float a0 = A0[(kk * 32 + kl) * DIM + j];
        float a1 = A1[(kk * 32 + kl) * DIM + j];
        LA[kl * 129 + j] = a0;
        LA[32 * 129 + kl * 129 + j] = a1 - a0;
    }

    float acc[2][2][4][4];
#pragma unroll
    for (int L = 0; L < 2; ++L)
#pragma unroll
        for (int R = 0; R < 2; ++R)
#pragma unroll
            for (int i = 0; i < 4; ++i)
#pragma unroll
                for (int mi = 0; mi < 4; ++mi) acc[L][R][i][mi] = 0.f;

    for (int ch = 0; ch < 4; ++ch) {
        __syncthreads();
        for (int c = tid; c < 32 * DIM; c += 256) {
            int jl = c >> 7, m = c & 127;
            float b0 = B0[(ch * 32 + jl) * DIM + m];
            float b1 = B1[(ch * 32 + jl) * DIM + m];
            LB[jl * 128 + m] = b0;
            LB[4096 + jl * 128 + m] = b1 - b0;
        }
        __syncthreads();
#pragma unroll 2
        for (int jl = 0; jl < 32; ++jl) {
            int j = ch * 32 + jl;
            float la0[4], la1[4];
#pragma unroll
            for (int i = 0; i < 4; ++i) {
                la0[i] = LA[(kgrp * 4 + i) * 129 + j];
                la1[i] = LA[32 * 129 + (kgrp * 4 + i) * 129 + j];
            }
            f32x4 lb0 = *reinterpret_cast<const f32x4*>(&LB[jl * 128 + mgrp * 4]);
            f32x4 lb1 = *reinterpret_cast<const f32x4*>(&LB[4096 + jl * 128 + mgrp * 4]);
#pragma unroll
            for (int i = 0; i < 4; ++i)
#pragma unroll
                for (int mi = 0; mi < 4; ++mi) {
                    acc[0][0][i][mi] += la0[i] * lb0[mi];
                    acc[1][0][i][mi] += la1[i] * lb0[mi];
                    acc[0][1][i][mi] += la0[i] * lb1[mi];
                    acc[1][1][i][mi] += la1[i] * lb1[mi];
                }
        }
    }

#pragma unroll
    for (int t = 0; t < 4; ++t) {
        int L = t & 1, R = t >> 1;
#pragma unroll
        for (int i = 0; i < 4; ++i)
#pragma unroll
            for (int mi = 0; mi < 4; ++mi) {
                int k = kk * 32 + kgrp * 4 + i;
                int m = mgrp * 4 + mi;
                int g = (k & 31) >> 3, j = k & 7;
                int lane = g * 16 + (m & 15);
                int mm = m >> 4;
                size_t idx =
                    ((((((size_t)p * 4 + t) * 4 + kk) * 8 + mm) * 64 + lane) * 8) + j;
                afrag[idx] = f2h(acc[L][R][i][mi]);
            }
    }
}

// ---------------------------------------------------------------------------
// prep 2: pack occupation bits, one u64 per batch row
// ---------------------------------------------------------------------------
__global__ void prep_bits(const int* __restrict__ onstate,
                          const int* __restrict__ image2,
                          u64* __restrict__ bits) {
    int r = blockIdx.x * blockDim.x + threadIdx.x;
    if (r >= BATCH_N) return;
    const int* row = onstate + (size_t)r * NS;
    u64 b = 0;
#pragma unroll 8
    for (int t = 0; t < NS; ++t) {
        b |= ((u64)(row[image2[t]] & 1)) << t;
    }
    bits[r] = b;
}

// ---------------------------------------------------------------------------
// main: 512 blocks x 512 threads (8 waves), 32 rows/block -> 2 blocks/CU,
// 4 waves/SIMD. Two independent barrier domains per CU overlap each other's
// latency gaps. Wave wid = m-tile (16 dims), rg in {0,1} row groups.
// A-term fragments streamed in kk-half chunks (2 in flight, 64 VGPR) to keep
// VGPR <= 128 so both blocks stay resident.
// ---------------------------------------------------------------------------
__global__ __launch_bounds__(512, 4)
void mps_pair(const unsigned short* __restrict__ afrag,
              const u64* __restrict__ occbits,
              const float* __restrict__ left,
              const float* __restrict__ right,
              float* __restrict__ out) {
    __shared__ unsigned short vlds[2][32 * DIM];   // 2 x 8 KB, fp16 v, swizzled
    __shared__ float red[32][33];                  // final reduction scratch

    const int tid  = threadIdx.x;
    const int wid  = tid >> 6;          // 0..7 -> m-tile
    const int lane = tid & 63;
    const int li   = lane & 15;
    const int g    = lane >> 4;
    const int rbase = blockIdx.x * 32;

    u64 bits[2];
#pragma unroll
    for (int rg = 0; rg < 2; ++rg)
        bits[rg] = occbits[rbase + rg * 16 + li];

    // hoisted LDS byte offsets (pair-invariant)
    u32 rdoff[2][4];
#pragma unroll
    for (int rg = 0; rg < 2; ++rg)
#pragma unroll
        for (int kk = 0; kk < 4; ++kk) {
            int r = rg * 16 + li;
            rdoff[rg][kk] =
                (u32)(r * 256 + kk * 64 + g * 16) ^ ((u32)(r & 7) << 4);
        }
    u32 wroff[2];
#pragma unroll
    for (int rg = 0; rg < 2; ++rg) {
        int r = rg * 16 + li;
        int mbase = wid * 16 + g * 4;
        wroff[rg] = (u32)(r * 256 + mbase * 2) ^ ((u32)(r & 7) << 4);
    }

    // init v buffer 0 with fp16(left), swizzled
    if (tid < 32 * 16) {
        int r  = tid >> 4;
        int kc = tid & 15;
        unsigned short tmp[8];
#pragma unroll
        for (int j = 0; j < 8; ++j) tmp[j] = f2h(left[kc * 8 + j]);
        u32 byte = (u32)(r * 256 + kc * 16) ^ ((u32)(r & 7) << 4);
        *reinterpret_cast<uint4*>(reinterpret_cast<char*>(&vlds[0][0]) + byte) =
            *reinterpret_cast<uint4*>(tmp);
    }
    __syncthreads();

    const f16x8 zf = {0, 0, 0, 0, 0, 0, 0, 0};

    f16x8 ft0[4][2], ft1[4][2];   // [term][kq] two kk-half chunk buffers
    f32x4 acc[2];

    // chunk c = 2p + h ; buffer parity == h (static)
#define ISSUE_CHUNK(FT, P_, H_)                                               \
    {                                                                         \
        const unsigned short* sb_ = afrag + (size_t)(P_) * 65536;             \
        _Pragma("unroll")                                                     \
        for (int t = 0; t < 4; ++t)                                           \
            _Pragma("unroll")                                                 \
            for (int kq = 0; kq < 2; ++kq)                                    \
                FT[t][kq] = *reinterpret_cast<const f16x8*>(                  \
                    sb_ +                                                     \
                    ((size_t)((t * 4 + 2 * (H_) + kq) * 8 + wid) * 512) +     \
                    lane * 8);                                                \
    }

#define COMPUTE_HALF(P_, H_, FT)                                              \
    {                                                                         \
        const int p_ = (P_);                                                  \
        const char* vb = reinterpret_cast<const char*>(&vlds[p_ & 1][0]);     \
        _Pragma("unroll")                                                     \
        for (int kq = 0; kq < 2; ++kq) {                                      \
            const int kk = 2 * (H_) + kq;                                     \
            f16x8 bfr[2];                                                     \
            _Pragma("unroll")                                                 \
            for (int rg = 0; rg < 2; ++rg)                                    \
                bfr[rg] =                                                     \
                    *reinterpret_cast<const f16x8*>(vb + rdoff[rg][kk]);      \
            _Pragma("unroll")                                                 \
            for (int rg = 0; rg < 2; ++rg) {                                  \
                bool m0 = (bits[rg] >> (2 * p_)) & 1;                         \
                bool m1 = (bits[rg] >> (2 * p_ + 1)) & 1;                     \
                f16x8 vb0  = m0 ? bfr[rg] : zf;                               \
                f16x8 vb1  = m1 ? bfr[rg] : zf;                               \
                f16x8 vb01 = m1 ? vb0 : zf;                                   \
                acc[rg] = __builtin_amdgcn_mfma_f32_16x16x32_f16(             \
                    FT[0][kq], bfr[rg], acc[rg], 0, 0, 0);                    \
                acc[rg] = __builtin_amdgcn_mfma_f32_16x16x32_f16(             \
                    FT[1][kq], vb0, acc[rg], 0, 0, 0);                        \
                acc[rg] = __builtin_amdgcn_mfma_f32_16x16x32_f16(             \
                    FT[2][kq], vb1, acc[rg], 0, 0, 0);                        \
                acc[rg] = __builtin_amdgcn_mfma_f32_16x16x32_f16(             \
                    FT[3][kq], vb01, acc[rg], 0, 0, 0);                       \
            }                                                                 \
        }                                                                     \
    }

#define WRITE_PHASE(P_)                                                       \
    {                                                                         \
        const int p_ = (P_);                                                  \
        char* wb = reinterpret_cast<char*>(&vlds[(p_ + 1) & 1][0]);           \
        if (p_ < NP - 1) {                                                    \
            _Pragma("unroll")                                                 \
            for (int rg = 0; rg < 2; ++rg) {                                  \
                u32 lo = ((u32)f2h(acc[rg][1]) << 16) | f2h(acc[rg][0]);      \
                u32 hi = ((u32)f2h(acc[rg][3]) << 16) | f2h(acc[rg][2]);      \
                uint2 w = {lo, hi};                                           \
                *reinterpret_cast<uint2*>(wb + wroff[rg]) = w;                \
            }                                                                 \
            __syncthreads();                                                  \
        } else {                                                              \
            int mcol = wid * 16 + g * 4;                                      \
            const float4 rv = *reinterpret_cast<const float4*>(right + mcol); \
            _Pragma("unroll")                                                 \
            for (int rg = 0; rg < 2; ++rg) {                                  \
                float pv = acc[rg][0] * rv.x + acc[rg][1] * rv.y +            \
                           acc[rg][2] * rv.z + acc[rg][3] * rv.w;             \
                red[rg * 16 + li][wid * 4 + g] = pv;                          \
            }                                                                 \
            __syncthreads();                                                  \
            if (tid < 32) {                                                   \
                float ssum = 0.f;                                             \
                _Pragma("unroll")                                             \
                for (int i = 0; i < 32; ++i) ssum += red[tid][i];             \
                out[rbase + tid] = ssum;                                      \
            }                                                                 \
        }                                                                     \
    }

    ISSUE_CHUNK(ft0, 0, 0);               // chunk c=0
    for (int p = 0; p < NP; ++p) {
        acc[0] = (f32x4){0.f, 0.f, 0.f, 0.f};
        acc[1] = (f32x4){0.f, 0.f, 0.f, 0.f};
        ISSUE_CHUNK(ft1, p, 1);           // chunk c=2p+1 (consumed this pair)
        COMPUTE_HALF(p, 0, ft0);
        if (p + 1 < NP) ISSUE_CHUNK(ft0, p + 1, 0);   // chunk c=2p+2
        COMPUTE_HALF(p, 1, ft1);
        WRITE_PHASE(p);
    }

#undef ISSUE_CHUNK
#undef COMPUTE_HALF
#undef WRITE_PHASE
}

// ---------------------------------------------------------------------------
extern "C" void kernel_launch(void* const* d_in, const int* in_sizes, int n_in,
                              void* d_out, int out_size, void* d_ws, size_t ws_size,
                              hipStream_t stream) {
    const int*   onstate = (const int*)d_in[0];
    const float* data    = (const float*)d_in[1];
    const float* left    = (const float*)d_in[2];
    const float* right   = (const float*)d_in[3];
    const int*   image2  = (const int*)d_in[4];
    float* out = (float*)d_out;

    unsigned short* afrag = (unsigned short*)d_ws;                       // 4 MB
    u64* bits = (u64*)((char*)d_ws + (size_t)2097152 * sizeof(unsigned short));

    prep_pair_frags<<<128, 256, 0, stream>>>(data, afrag);
    prep_bits<<<64, 256, 0, stream>>>(onstate, image2, bits);
    mps_pair<<<512, 512, 0, stream>>>(afrag, bits, left, right, out);
}

// Round 8
// 118.734 us; speedup vs baseline: 1.0685x; 1.0685x over previous
//
#include <hip/hip_runtime.h>
#include <hip/hip_bf16.h>

#define NS 64
#define NP 32
#define DIM 128
#define BATCH_N 16384

typedef float f32x4 __attribute__((ext_vector_type(4)));
typedef _Float16 f16x8 __attribute__((ext_vector_type(8)));
typedef __fp16 fp16x2 __attribute__((ext_vector_type(2)));
typedef unsigned int u32;
typedef unsigned long long u64;

// fp32 -> fp16 (RNE via hardware cvt)
__device__ __forceinline__ unsigned short f2h(float f) {
    _Float16 h = (_Float16)f;
    return __builtin_bit_cast(unsigned short, h);
}

// ---------------------------------------------------------------------------
// prep 1: pair-compressed fp16 MFMA A-operand fragments.
// Pair p combines sites s0=2p, s1=2p+1. Terms:
//   t0 = A0@B0            t1 = (A1-A0)@B0      (factor b0)
//   t2 = A0@(B1-B0)       t3 = (A1-A0)@(B1-B0) (factor b0*b1)
// Layout (saddr-friendly): element index =
//   ((((p*8 + mm)*2 + H)*4 + t)*2 + kq)*512 + lane*8 + j
// where kk = 2H+kq, k = kk*32 + (lane>>4)*8 + j, m = mm*16 + (lane&15).
// Grid: 256 blocks = (p 32) x (kk 4) x (m-half 2); 256 thr = kgrp16 x mgrp16,
// thread tile k2 x m4, fp32 MACs, operands LDS-staged.
// ---------------------------------------------------------------------------
__global__ __launch_bounds__(256)
void prep_pair_frags(const float* __restrict__ data,
                     unsigned short* __restrict__ afrag) {
    __shared__ float LA[2 * 32 * 129];   // [L][kl][j], pad 129
    __shared__ float LB[2 * 32 * 68];    // [R][jl][ml], pad 68 (16B-aligned rows)

    const int p   = blockIdx.x >> 3;
    const int kk  = (blockIdx.x >> 1) & 3;
    const int mh  = blockIdx.x & 1;
    const int tid = threadIdx.x;
    const int kgrp = tid >> 4;          // 0..15, k-tile 2
    const int mgrp = tid & 15;          // 0..15, m-tile 4

    const float* A0 = data + ((size_t)(2 * p) * 2 + 0) * DIM * DIM;
    const float* A1 = A0 + DIM * DIM;
    const float* B0 = data + ((size_t)(2 * p + 1) * 2 + 0) * DIM * DIM;
    const float* B1 = B0 + DIM * DIM;

    // stage LA rows k in [kk*32, kk*32+32), all 128 j
    for (int c = tid; c < 32 * DIM; c += 256) {
        int kl = c >> 7, j = c & 127;
        float a0 = A0[(kk * 32 + kl) * DIM + j];
        float a1 = A1[(kk * 32 + kl) * DIM + j];
        LA[kl * 129 + j] = a0;
        LA[32 * 129 + kl * 129 + j] = a1 - a0;
    }

    float acc[2][2][2][4];   // [L][R][i][mi]
#pragma unroll
    for (int L = 0; L < 2; ++L)
#pragma unroll
        for (int R = 0; R < 2; ++R)
#pragma unroll
            for (int i = 0; i < 2; ++i)
#pragma unroll
                for (int mi = 0; mi < 4; ++mi) acc[L][R][i][mi] = 0.f;

    for (int ch = 0; ch < 4; ++ch) {
        __syncthreads();
        // stage LB j-rows [ch*32, ch*32+32), m-cols [mh*64, mh*64+64)
        for (int c = tid; c < 32 * 64; c += 256) {
            int jl = c >> 6, ml = c & 63;
            float b0 = B0[(ch * 32 + jl) * DIM + mh * 64 + ml];
            float b1 = B1[(ch * 32 + jl) * DIM + mh * 64 + ml];
            LB[jl * 68 + ml] = b0;
            LB[32 * 68 + jl * 68 + ml] = b1 - b0;
        }
        __syncthreads();
#pragma unroll 2
        for (int jl = 0; jl < 32; ++jl) {
            int j = ch * 32 + jl;
            float la0[2], la1[2];
#pragma unroll
            for (int i = 0; i < 2; ++i) {
                la0[i] = LA[(kgrp * 2 + i) * 129 + j];
                la1[i] = LA[32 * 129 + (kgrp * 2 + i) * 129 + j];
            }
            f32x4 lb0 = *reinterpret_cast<const f32x4*>(&LB[jl * 68 + mgrp * 4]);
            f32x4 lb1 = *reinterpret_cast<const f32x4*>(&LB[32 * 68 + jl * 68 + mgrp * 4]);
#pragma unroll
            for (int i = 0; i < 2; ++i)
#pragma unroll
                for (int mi = 0; mi < 4; ++mi) {
                    acc[0][0][i][mi] += la0[i] * lb0[mi];
                    acc[1][0][i][mi] += la1[i] * lb0[mi];
                    acc[0][1][i][mi] += la0[i] * lb1[mi];
                    acc[1][1][i][mi] += la1[i] * lb1[mi];
                }
        }
    }

    const int H   = kk >> 1;
    const int kq  = kk & 1;
#pragma unroll
    for (int t = 0; t < 4; ++t) {
        int L = t & 1, R = t >> 1;
#pragma unroll
        for (int i = 0; i < 2; ++i)
#pragma unroll
            for (int mi = 0; mi < 4; ++mi) {
                int k = kk * 32 + kgrp * 2 + i;
                int m = mh * 64 + mgrp * 4 + mi;
                int mm = m >> 4;
                int lane = ((k & 31) >> 3) * 16 + (m & 15);
                int jj = k & 7;
                size_t idx =
                    ((size_t)((((p * 8 + mm) * 2 + H) * 4 + t) * 2 + kq)) * 512 +
                    lane * 8 + jj;
                afrag[idx] = f2h(acc[L][R][i][mi]);
            }
    }
}

// ---------------------------------------------------------------------------
// prep 2: pack occupation bits, one u64 per batch row
// ---------------------------------------------------------------------------
__global__ void prep_bits(const int* __restrict__ onstate,
                          const int* __restrict__ image2,
                          u64* __restrict__ bits) {
    int r = blockIdx.x * blockDim.x + threadIdx.x;
    if (r >= BATCH_N) return;
    const int* row = onstate + (size_t)r * NS;
    u64 b = 0;
#pragma unroll 8
    for (int t = 0; t < NS; ++t) {
        b |= ((u64)(row[image2[t]] & 1)) << t;
    }
    bits[r] = b;
}

// ---------------------------------------------------------------------------
// main: 512 blocks x 512 threads (8 waves), 32 rows/block -> 2 blocks/CU,
// 4 waves/SIMD. Fragment loads: uniform SGPR base (per phase) + hoisted
// per-lane voffset + imm offsets (<=4KB) -> zero in-loop address VALU.
// setprio(1) around the MFMA clusters (two blocks/CU give role diversity).
// ---------------------------------------------------------------------------
__global__ __launch_bounds__(512, 4)
void mps_pair(const unsigned short* __restrict__ afrag,
              const u64* __restrict__ occbits,
              const float* __restrict__ left,
              const float* __restrict__ right,
              float* __restrict__ out) {
    __shared__ unsigned short vlds[2][32 * DIM];   // 2 x 8 KB, fp16 v, swizzled
    __shared__ float red[32][33];                  // final reduction scratch

    const int tid  = threadIdx.x;
    const int wid  = tid >> 6;          // 0..7 -> m-tile
    const int lane = tid & 63;
    const int li   = lane & 15;
    const int g    = lane >> 4;
    const int rbase = blockIdx.x * 32;

    u64 bits[2];
#pragma unroll
    for (int rg = 0; rg < 2; ++rg)
        bits[rg] = occbits[rbase + rg * 16 + li];

    // hoisted per-lane fragment voffsets (element units), +2048 folds imm range
    const int voff0 = wid * 8192 + 2048 + lane * 8;   // half 0
    const int voff1 = voff0 + 4096;                   // half 1

    // hoisted LDS byte offsets (pair-invariant)
    u32 rdoff[2][4];
#pragma unroll
    for (int rg = 0; rg < 2; ++rg)
#pragma unroll
        for (int kk = 0; kk < 4; ++kk) {
            int r = rg * 16 + li;
            rdoff[rg][kk] =
                (u32)(r * 256 + kk * 64 + g * 16) ^ ((u32)(r & 7) << 4);
        }
    u32 wroff[2];
#pragma unroll
    for (int rg = 0; rg < 2; ++rg) {
        int r = rg * 16 + li;
        int mbase = wid * 16 + g * 4;
        wroff[rg] = (u32)(r * 256 + mbase * 2) ^ ((u32)(r & 7) << 4);
    }

    // init v buffer 0 with fp16(left), swizzled
    if (tid < 32 * 16) {
        int r  = tid >> 4;
        int kc = tid & 15;
        unsigned short tmp[8];
#pragma unroll
        for (int j = 0; j < 8; ++j) tmp[j] = f2h(left[kc * 8 + j]);
        u32 byte = (u32)(r * 256 + kc * 16) ^ ((u32)(r & 7) << 4);
        *reinterpret_cast<uint4*>(reinterpret_cast<char*>(&vlds[0][0]) + byte) =
            *reinterpret_cast<uint4*>(tmp);
    }
    __syncthreads();

    const f16x8 zf = {0, 0, 0, 0, 0, 0, 0, 0};

    f16x8 ft0[4][2], ft1[4][2];   // [t][kq] two half-chunk buffers
    f32x4 acc[2];

#define ISSUE_CHUNK(FT, PB, VOFF)                                             \
    {                                                                         \
        _Pragma("unroll")                                                     \
        for (int t = 0; t < 4; ++t)                                           \
            _Pragma("unroll")                                                 \
            for (int kq = 0; kq < 2; ++kq)                                    \
                FT[t][kq] = *reinterpret_cast<const f16x8*>(                  \
                    (PB) + (VOFF) + (t * 1024 + kq * 512 - 2048));            \
    }

#define COMPUTE_HALF(P_, H_, FT)                                              \
    {                                                                         \
        const int p_ = (P_);                                                  \
        const char* vb = reinterpret_cast<const char*>(&vlds[p_ & 1][0]);     \
        __builtin_amdgcn_s_setprio(1);                                        \
        _Pragma("unroll")                                                     \
        for (int kq = 0; kq < 2; ++kq) {                                      \
            const int kk = 2 * (H_) + kq;                                     \
            f16x8 bfr[2];                                                     \
            _Pragma("unroll")                                                 \
            for (int rg = 0; rg < 2; ++rg)                                    \
                bfr[rg] =                                                     \
                    *reinterpret_cast<const f16x8*>(vb + rdoff[rg][kk]);      \
            _Pragma("unroll")                                                 \
            for (int rg = 0; rg < 2; ++rg) {                                  \
                bool m0 = (bits[rg] >> (2 * p_)) & 1;                         \
                bool m1 = (bits[rg] >> (2 * p_ + 1)) & 1;                     \
                f16x8 vb0  = m0 ? bfr[rg] : zf;                               \
                f16x8 vb1  = m1 ? bfr[rg] : zf;                               \
                f16x8 vb01 = m1 ? vb0 : zf;                                   \
                acc[rg] = __builtin_amdgcn_mfma_f32_16x16x32_f16(             \
                    FT[0][kq], bfr[rg], acc[rg], 0, 0, 0);                    \
                acc[rg] = __builtin_amdgcn_mfma_f32_16x16x32_f16(             \
                    FT[1][kq], vb0, acc[rg], 0, 0, 0);                        \
                acc[rg] = __builtin_amdgcn_mfma_f32_16x16x32_f16(             \
                    FT[2][kq], vb1, acc[rg], 0, 0, 0);                        \
                acc[rg] = __builtin_amdgcn_mfma_f32_16x16x32_f16(             \
                    FT[3][kq], vb01, acc[rg], 0, 0, 0);                       \
            }                                                                 \
        }                                                                     \
        __builtin_amdgcn_s_setprio(0);                                        \
    }

#define WRITE_PHASE(P_)                                                       \
    {                                                                         \
        const int p_ = (P_);                                                  \
        char* wb = reinterpret_cast<char*>(&vlds[(p_ + 1) & 1][0]);           \
        if (p_ < NP - 1) {                                                    \
            _Pragma("unroll")                                                 \
            for (int rg = 0; rg < 2; ++rg) {                                  \
                fp16x2 h01 = __builtin_amdgcn_cvt_pkrtz(acc[rg][0], acc[rg][1]); \
                fp16x2 h23 = __builtin_amdgcn_cvt_pkrtz(acc[rg][2], acc[rg][3]); \
                uint2 w = {__builtin_bit_cast(u32, h01),                      \
                           __builtin_bit_cast(u32, h23)};                     \
                *reinterpret_cast<uint2*>(wb + wroff[rg]) = w;                \
            }                                                                 \
            __syncthreads();                                                  \
        } else {                                                              \
            int mcol = wid * 16 + g * 4;                                      \
            const float4 rv = *reinterpret_cast<const float4*>(right + mcol); \
            _Pragma("unroll")                                                 \
            for (int rg = 0; rg < 2; ++rg) {                                  \
                float pv = acc[rg][0] * rv.x + acc[rg][1] * rv.y +            \
                           acc[rg][2] * rv.z + acc[rg][3] * rv.w;             \
                red[rg * 16 + li][wid * 4 + g] = pv;                          \
            }                                                                 \
            __syncthreads();                                                  \
            if (tid < 32) {                                                   \
                float ssum = 0.f;                                             \
                _Pragma("unroll")                                             \
                for (int i = 0; i < 32; ++i) ssum += red[tid][i];             \
                out[rbase + tid] = ssum;                                      \
            }                                                                 \
        }                                                                     \
    }

    ISSUE_CHUNK(ft0, afrag, voff0);                  // pair 0, half 0
    for (int p = 0; p < NP; ++p) {
        const unsigned short* pb = afrag + ((size_t)p << 16);   // uniform
        acc[0] = (f32x4){0.f, 0.f, 0.f, 0.f};
        acc[1] = (f32x4){0.f, 0.f, 0.f, 0.f};
        ISSUE_CHUNK(ft1, pb, voff1);                 // half 1 of pair p
        COMPUTE_HALF(p, 0, ft0);
        if (p + 1 < NP) {
            const unsigned short* pbn = pb + 65536;
            ISSUE_CHUNK(ft0, pbn, voff0);            // half 0 of pair p+1
        }
        COMPUTE_HALF(p, 1, ft1);
        WRITE_PHASE(p);
    }

#undef ISSUE_CHUNK
#undef COMPUTE_HALF
#undef WRITE_PHASE
}

// ---------------------------------------------------------------------------
extern "C" void kernel_launch(void* const* d_in, const int* in_sizes, int n_in,
                              void* d_out, int out_size, void* d_ws, size_t ws_size,
                              hipStream_t stream) {
    const int*   onstate = (const int*)d_in[0];
    const float* data    = (const float*)d_in[1];
    const float* left    = (const float*)d_in[2];
    const float* right   = (const float*)d_in[3];
    const int*   image2  = (const int*)d_in[4];
    float* out = (float*)d_out;

    unsigned short* afrag = (unsigned short*)d_ws;                       // 4 MB
    u64* bits = (u64*)((char*)d_ws + (size_t)2097152 * sizeof(unsigned short));

    prep_pair_frags<<<256, 256, 0, stream>>>(data, afrag);
    prep_bits<<<64, 256, 0, stream>>>(onstate, image2, bits);
    mps_pair<<<512, 512, 0, stream>>>(afrag, bits, left, right, out);
}